// Round 1
// baseline (5515.601 us; speedup 1.0000x reference)
//
#include <hip/hip_runtime.h>

// GeneratorNetwork: persistent cooperative kernel.
// Grid = 256 WGs = 16 batch-strips (64 rows) x 16 gate-slices (16 h-channels).
// All LSTM weights live in registers as f16 MFMA B-fragments (96KB/WG).
// Cross-WG h exchange through LLC with agent-scope atomics + per-strip flags.

typedef _Float16 f16;
typedef _Float16 f16x8 __attribute__((ext_vector_type(8)));
typedef _Float16 f16x4v __attribute__((ext_vector_type(4)));
typedef float f32x4 __attribute__((ext_vector_type(4)));
typedef unsigned long long u64;
typedef unsigned int u32;

#define TSTEPS 256

__device__ __forceinline__ float sigf(float x){ return 1.0f/(1.0f+__expf(-x)); }
__device__ __forceinline__ float tanhc(float x){
  x = fminf(fmaxf(x, -40.0f), 40.0f);
  float e = __expf(2.0f*x);
  return (e-1.0f)/(e+1.0f);
}

// B-fragment for mfma_f32_16x16x32_f16: lane holds W[n0+(l&15)][k0 + (l>>4)*8 + j]
__device__ __forceinline__ f16x8 load_w_frag(const float* __restrict__ W, int row, int k0){
  const float4* p = (const float4*)(W + row*256 + k0);
  float4 a = p[0], b = p[1];
  f16x8 v;
  v[0]=(f16)a.x; v[1]=(f16)a.y; v[2]=(f16)a.z; v[3]=(f16)a.w;
  v[4]=(f16)b.x; v[5]=(f16)b.y; v[6]=(f16)b.z; v[7]=(f16)b.w;
  return v;
}

extern "C" __global__ void __launch_bounds__(256, 1)
gen_lstm_persistent(
    const float* __restrict__ noise, const float* __restrict__ Wup,
    const float* __restrict__ bup,
    const float* __restrict__ Wih0, const float* __restrict__ Whh0,
    const float* __restrict__ bih0, const float* __restrict__ bhh0,
    const float* __restrict__ Wih1, const float* __restrict__ Whh1,
    const float* __restrict__ bih1, const float* __restrict__ bhh1,
    const float* __restrict__ gam_a, const float* __restrict__ bet_a,
    const float* __restrict__ Wa, const float* __restrict__ ba,
    const float* __restrict__ gam_w, const float* __restrict__ bet_w,
    const float* __restrict__ Ww, const float* __restrict__ bw,
    float* __restrict__ out,
    u32* flags, u64* H0X, u64* H1X)
{
  __shared__ __align__(16) unsigned char SMEM[52800];
  f16*   h1s    = (f16*)SMEM;                   // [64][256] f16 (32768B); also noise stage
  float* gates  = (float*)(SMEM + 32768);       // [64][68] f32 (17408B)
  f16*   va16   = (f16*)(SMEM + 50176);         // gamma_a*Wa (512B)
  f16*   vw16   = (f16*)(SMEM + 50688);         // gamma_w*Ww (512B)
  float* coords = (float*)(SMEM + 51200);       // [64][2] f32 (512B)
  float* tmp    = (float*)(SMEM + 51712);       // [256] f32
  float* sc     = (float*)(SMEM + 52736);       // [0]=Ca [1]=Cw [2..5]=gsum_a [6..9]=gsum_w

  const int tid = threadIdx.x;
  const int s = blockIdx.x >> 4;      // batch strip: rows [64s, 64s+64)
  const int q = blockIdx.x & 15;      // slice: h-channels [16q, 16q+16)
  const int lane = tid & 63;
  const int wv = tid >> 6;            // 4 waves: 2 m-groups x 2 n-groups
  const int mg = wv >> 1, ng = wv & 1;
  const int rl = lane & 15, kh = lane >> 4;
  const int er = tid & 63, eq = tid >> 6;   // elementwise mapping: row er, ch quad eq

  // ---- small constants ----
  va16[tid] = (f16)(gam_a[tid]*Wa[tid]);
  vw16[tid] = (f16)(gam_w[tid]*Ww[tid]);
  tmp[tid]  = bet_a[tid]*Wa[tid];
  __syncthreads();
  if (tid==0){ float v=0; for (int c=0;c<256;++c) v+=tmp[c]; sc[0]=v+ba[0]; }
  if (tid==1){
    for (int g=0; g<4; ++g){ float v=0; for (int c=0;c<64;++c) v+=(float)va16[g*64+c]; sc[2+g]=v; }
    for (int g=0; g<4; ++g){ float v=0; for (int c=0;c<64;++c) v+=(float)vw16[g*64+c]; sc[6+g]=v; }
  }
  __syncthreads();
  tmp[tid] = bet_w[tid]*Ww[tid];
  __syncthreads();
  if (tid==0){ float v=0; for (int c=0;c<256;++c) v+=tmp[c]; sc[1]=v+bw[0]; }

  // ---- weight fragments -> registers (persistent) ----
  // gate row for (local ch j, gate g in {i,f,g,o}) = 16q + j + 256g ; n-tile == gate type.
  f16x8 wf0[2][8], wf1[2][8], wf2[2][8];  // Whh0, Wih1, Whh1
  float b0r[2], b1r[2], w00[2], w01[2];
  #pragma unroll
  for (int nt=0; nt<2; ++nt){
    const int g = ng*2 + nt;
    const int row = q*16 + rl + 256*g;
    b0r[nt] = bih0[row] + bhh0[row];
    b1r[nt] = bih1[row] + bhh1[row];
    w00[nt] = Wih0[row*2+0];
    w01[nt] = Wih0[row*2+1];
    #pragma unroll
    for (int kk=0; kk<8; ++kk){
      const int k0 = kk*32 + kh*8;
      wf0[nt][kk] = load_w_frag(Whh0, row, k0);
      wf1[nt][kk] = load_w_frag(Wih1, row, k0);
      wf2[nt][kk] = load_w_frag(Whh1, row, k0);
    }
  }

  // ---- initial state: idea = elu(noise @ Wup^T + bup) (fp32 VALU, one-time) ----
  float* nstage = (float*)SMEM;   // [64][128] f32, overlaps h1s region
  #pragma unroll
  for (int i=0;i<8;++i){
    int flat = i*256 + tid;
    int r = flat >> 5, c4 = flat & 31;
    ((float4*)nstage)[flat] = ((const float4*)noise)[(s*64+r)*32 + c4];
  }
  __syncthreads();
  {
    float acc[64];
    #pragma unroll
    for (int r=0;r<64;++r) acc[r]=0.0f;
    const float4* wrow = (const float4*)(Wup + tid*128);   // thread owns channel tid
    for (int kk=0; kk<16; ++kk){
      float4 wa4 = wrow[kk*2], wb4 = wrow[kk*2+1];
      #pragma unroll
      for (int r=0;r<64;++r){
        const float4* np = (const float4*)(nstage + r*128 + kk*8);
        float4 na = np[0], nb = np[1];
        acc[r] += na.x*wa4.x + na.y*wa4.y + na.z*wa4.z + na.w*wa4.w
                + nb.x*wb4.x + nb.y*wb4.y + nb.z*wb4.z + nb.w*wb4.w;
      }
    }
    float bu = bup[tid];
    __syncthreads();   // noise reads done; reuse region as f16 idea [64][256]
    #pragma unroll
    for (int r=0;r<64;++r){
      float v = acc[r] + bu;
      v = (v > 0.0f) ? v : (__expf(v) - 1.0f);
      h1s[r*256 + tid] = (f16)v;
    }
  }
  __syncthreads();

  // A-fragments: h0 = idea, h1 = 0; c0 = idea(slice), c1 = 0
  f16x8 h0f[2][8], h1f[2][8];
  #pragma unroll
  for (int mt=0;mt<2;++mt)
  #pragma unroll
  for (int kk=0;kk<8;++kk){
    const int m = (mg*2+mt)*16 + rl;
    const int k0 = kk*32 + kh*8;
    h0f[mt][kk] = *(const f16x8*)(h1s + m*256 + k0);
    f16x8 z;
    #pragma unroll
    for (int j=0;j<8;++j) z[j]=(f16)0.0f;
    h1f[mt][kk] = z;
  }
  float c0v[4], c1v[4];
  {
    f16x4v hv = *(const f16x4v*)(h1s + er*256 + q*16 + eq*4);
    #pragma unroll
    for (int i=0;i<4;++i){ c0v[i] = (float)hv[i]; c1v[i] = 0.0f; }
  }
  if (tid < 128) coords[tid] = 0.0f;
  __syncthreads();

  u32* flagA = flags + s*64;        // 256B stride per strip
  u32* flagB = flags + s*64 + 32;   // +128B

  for (int t=0; t<TSTEPS; ++t){
    // ===== Phase A: gates0 = h0_prev @ Whh0^T (+ coords@Wih0^T + bias in epilogue) =====
    f32x4 acc0[2][2];
    #pragma unroll
    for (int mt=0;mt<2;++mt)
    #pragma unroll
    for (int nt=0;nt<2;++nt){ f32x4 z = {0.f,0.f,0.f,0.f}; acc0[mt][nt]=z; }
    #pragma unroll
    for (int kk=0;kk<8;++kk)
    #pragma unroll
    for (int mt=0;mt<2;++mt){
      acc0[mt][0] = __builtin_amdgcn_mfma_f32_16x16x32_f16(h0f[mt][kk], wf0[0][kk], acc0[mt][0],0,0,0);
      acc0[mt][1] = __builtin_amdgcn_mfma_f32_16x16x32_f16(h0f[mt][kk], wf0[1][kk], acc0[mt][1],0,0,0);
    }
    #pragma unroll
    for (int mt=0;mt<2;++mt)
    #pragma unroll
    for (int nt=0;nt<2;++nt){
      const int col = (ng*2+nt)*16 + rl;
      #pragma unroll
      for (int r4=0;r4<4;++r4){
        const int m = (mg*2+mt)*16 + kh*4 + r4;   // D: col=lane&15, row=(lane>>4)*4+reg
        gates[m*68 + col] = acc0[mt][nt][r4] + b0r[nt]
                          + coords[m*2]*w00[nt] + coords[m*2+1]*w01[nt];
      }
    }
    __syncthreads();
    // elementwise cell 0 -> c0, h0'; publish slice to LLC
    {
      const float* gr = gates + er*68 + eq*4;
      float gi[4], gf[4], gg[4], go[4];
      *(float4*)gi = *(const float4*)(gr);
      *(float4*)gf = *(const float4*)(gr+16);
      *(float4*)gg = *(const float4*)(gr+32);
      *(float4*)go = *(const float4*)(gr+48);
      union { u64 u; f16 h[4]; } pk;
      #pragma unroll
      for (int i=0;i<4;++i){
        float cn = sigf(gf[i])*c0v[i] + sigf(gi[i])*tanhc(gg[i]);
        c0v[i] = cn;
        pk.h[i] = (f16)(sigf(go[i])*tanhc(cn));
      }
      __hip_atomic_store(H0X + ((u64)(s*64+er)*64 + q*4 + eq), pk.u,
                         __ATOMIC_RELAXED, __HIP_MEMORY_SCOPE_AGENT);
    }
    __syncthreads();   // drains each thread's stores (vmcnt) before flag
    if (tid==0) __hip_atomic_fetch_add(flagA, 1u, __ATOMIC_RELEASE, __HIP_MEMORY_SCOPE_AGENT);

    // ===== Phase A' (off critical path): acc1 = h1_prev @ Whh1^T =====
    f32x4 acc1[2][2];
    #pragma unroll
    for (int mt=0;mt<2;++mt)
    #pragma unroll
    for (int nt=0;nt<2;++nt){ f32x4 z = {0.f,0.f,0.f,0.f}; acc1[mt][nt]=z; }
    #pragma unroll
    for (int kk=0;kk<8;++kk)
    #pragma unroll
    for (int mt=0;mt<2;++mt){
      acc1[mt][0] = __builtin_amdgcn_mfma_f32_16x16x32_f16(h1f[mt][kk], wf2[0][kk], acc1[mt][0],0,0,0);
      acc1[mt][1] = __builtin_amdgcn_mfma_f32_16x16x32_f16(h1f[mt][kk], wf2[1][kk], acc1[mt][1],0,0,0);
    }

    // wait for all h0 slices of this strip
    if (tid==0){
      while (__hip_atomic_load(flagA, __ATOMIC_RELAXED, __HIP_MEMORY_SCOPE_AGENT) < (u32)(16*(t+1)))
        __builtin_amdgcn_s_sleep(2);
    }
    __syncthreads();

    // reload h0 fragments from LLC exchange
    #pragma unroll
    for (int mt=0;mt<2;++mt)
    #pragma unroll
    for (int kk=0;kk<8;++kk){
      const int m = (mg*2+mt)*16 + rl;
      const u64 i0 = (u64)(s*64+m)*64 + kk*8 + kh*2;
      union { u64 u[2]; f16x8 v; } cv;
      cv.u[0] = __hip_atomic_load(H0X + i0,     __ATOMIC_RELAXED, __HIP_MEMORY_SCOPE_AGENT);
      cv.u[1] = __hip_atomic_load(H0X + i0 + 1, __ATOMIC_RELAXED, __HIP_MEMORY_SCOPE_AGENT);
      h0f[mt][kk] = cv.v;
    }
    // ===== Phase B: acc1 += h0_new @ Wih1^T =====
    #pragma unroll
    for (int kk=0;kk<8;++kk)
    #pragma unroll
    for (int mt=0;mt<2;++mt){
      acc1[mt][0] = __builtin_amdgcn_mfma_f32_16x16x32_f16(h0f[mt][kk], wf1[0][kk], acc1[mt][0],0,0,0);
      acc1[mt][1] = __builtin_amdgcn_mfma_f32_16x16x32_f16(h0f[mt][kk], wf1[1][kk], acc1[mt][1],0,0,0);
    }
    #pragma unroll
    for (int mt=0;mt<2;++mt)
    #pragma unroll
    for (int nt=0;nt<2;++nt){
      const int col = (ng*2+nt)*16 + rl;
      #pragma unroll
      for (int r4=0;r4<4;++r4){
        const int m = (mg*2+mt)*16 + kh*4 + r4;
        gates[m*68 + col] = acc1[mt][nt][r4] + b1r[nt];
      }
    }
    __syncthreads();
    // elementwise cell 1 -> c1, h1'
    {
      const float* gr = gates + er*68 + eq*4;
      float gi[4], gf[4], gg[4], go[4];
      *(float4*)gi = *(const float4*)(gr);
      *(float4*)gf = *(const float4*)(gr+16);
      *(float4*)gg = *(const float4*)(gr+32);
      *(float4*)go = *(const float4*)(gr+48);
      union { u64 u; f16 h[4]; } pk;
      #pragma unroll
      for (int i=0;i<4;++i){
        float cn = sigf(gf[i])*c1v[i] + sigf(gi[i])*tanhc(gg[i]);
        c1v[i] = cn;
        pk.h[i] = (f16)(sigf(go[i])*tanhc(cn));
      }
      __hip_atomic_store(H1X + ((u64)(s*64+er)*64 + q*4 + eq), pk.u,
                         __ATOMIC_RELAXED, __HIP_MEMORY_SCOPE_AGENT);
    }
    __syncthreads();
    if (tid==0){
      __hip_atomic_fetch_add(flagB, 1u, __ATOMIC_RELEASE, __HIP_MEMORY_SCOPE_AGENT);
      while (__hip_atomic_load(flagB, __ATOMIC_RELAXED, __HIP_MEMORY_SCOPE_AGENT) < (u32)(16*(t+1)))
        __builtin_amdgcn_s_sleep(2);
    }
    __syncthreads();

    // ===== Phase C: pull full h1 (LDS for GN + regs for next A'), GroupNorm -> coords =====
    #pragma unroll
    for (int i=0;i<16;++i){
      const int flat = i*256 + tid;
      ((u64*)SMEM)[flat] = __hip_atomic_load(H1X + (u64)s*4096 + flat,
                           __ATOMIC_RELAXED, __HIP_MEMORY_SCOPE_AGENT);
    }
    #pragma unroll
    for (int mt=0;mt<2;++mt)
    #pragma unroll
    for (int kk=0;kk<8;++kk){
      const int m = (mg*2+mt)*16 + rl;
      const u64 i0 = (u64)(s*64+m)*64 + kk*8 + kh*2;
      union { u64 u[2]; f16x8 v; } cv;
      cv.u[0] = __hip_atomic_load(H1X + i0,     __ATOMIC_RELAXED, __HIP_MEMORY_SCOPE_AGENT);
      cv.u[1] = __hip_atomic_load(H1X + i0 + 1, __ATOMIC_RELAXED, __HIP_MEMORY_SCOPE_AGENT);
      h1f[mt][kk] = cv.v;
    }
    __syncthreads();
    {
      const int r = tid >> 2, g = tid & 3;   // 4 lanes per row (same wave), one group each
      float sx=0.f, sxx=0.f, sva=0.f, svw=0.f;
      #pragma unroll
      for (int c8=0;c8<8;++c8){
        const int idx = (c8 + r) & 7;        // rotate chunks to spread LDS banks
        const int ch = g*64 + idx*8;
        f16x8 xv  = *(const f16x8*)(h1s + r*256 + ch);
        f16x8 av  = *(const f16x8*)(va16 + ch);
        f16x8 wv8 = *(const f16x8*)(vw16 + ch);
        #pragma unroll
        for (int j=0;j<8;++j){
          float x = (float)xv[j];
          sx += x; sxx += x*x;
          sva += x*(float)av[j];
          svw += x*(float)wv8[j];
        }
      }
      const float mean = sx*(1.0f/64.0f);
      float var = sxx*(1.0f/64.0f) - mean*mean;
      var = fmaxf(var, 0.0f);
      const float rstd = rsqrtf(var + 1e-5f);
      float pa = (sva - mean*sc[2+g])*rstd;
      float pw = (svw - mean*sc[6+g])*rstd;
      pa += __shfl_xor(pa, 1); pa += __shfl_xor(pa, 2);
      pw += __shfl_xor(pw, 1); pw += __shfl_xor(pw, 2);
      if (g == 0){
        const float ang = tanhc(pa + sc[0]);
        const float wid = sigf(pw + sc[1]);
        coords[r*2] = ang; coords[r*2+1] = wid;
        if (q == 0){
          out[(s*64+r)*512 + t*2]     = ang;
          out[(s*64+r)*512 + t*2 + 1] = wid;
        }
      }
    }
    __syncthreads();
  }
}

extern "C" void kernel_launch(void* const* d_in, const int* in_sizes, int n_in,
                              void* d_out, int out_size, void* d_ws, size_t ws_size,
                              hipStream_t stream){
  (void)in_sizes; (void)n_in; (void)out_size; (void)ws_size;
  // flags region must be zero every launch (monotonic counters)
  hipMemsetAsync(d_ws, 0, 4096, stream);
  u32* flags = (u32*)d_ws;
  u64* H0X = (u64*)((char*)d_ws + 8192);              // 512KB h0 exchange (f16)
  u64* H1X = (u64*)((char*)d_ws + 8192 + 524288);     // 512KB h1 exchange (f16)
  gen_lstm_persistent<<<dim3(256), dim3(256), 0, stream>>>(
    (const float*)d_in[0],  (const float*)d_in[1],  (const float*)d_in[2],
    (const float*)d_in[3],  (const float*)d_in[4],  (const float*)d_in[5],
    (const float*)d_in[6],  (const float*)d_in[7],  (const float*)d_in[8],
    (const float*)d_in[9],  (const float*)d_in[10], (const float*)d_in[11],
    (const float*)d_in[12], (const float*)d_in[13], (const float*)d_in[14],
    (const float*)d_in[15], (const float*)d_in[16], (const float*)d_in[17],
    (const float*)d_in[18],
    (float*)d_out, flags, H0X, H1X);
}